// Round 7
// baseline (5766.678 us; speedup 1.0000x reference)
//
#include <hip/hip_runtime.h>

// Handwriting synthesis RNN — persistent fused kernel, R10.
// R10 vs R9 post-mortem: 6 rounds of structural changes (work removal, sync
// mechanics, broadcast halving, AGPR residency) all land within +-5% — the
// ~6.9us/step is ~2.4x my 2.4GHz floor arithmetic, uniformly across
// variants. Hypothesis: DPM downclock (6% VALU util on a 1400W part -> low
// SCLK state) inflates every latency and every compute phase by a constant
// factor. R10 = R9 byte-identical real blocks + 120 HEATER blocks (grid
// 136->256): pure-VALU register FMA spinners, no memory traffic except a
// done-flag poll every ~8us, terminated by role2 blocks bumping a done
// counter. Clean A/B: if clock theory right, dur drops >=10%; if flat,
// clocks are exonerated and the structure is at its latency floor.

typedef unsigned short u16;
typedef unsigned int   u32;
typedef unsigned long long u64;
typedef u16   u16x8  __attribute__((ext_vector_type(8)));
typedef u32   u32x2  __attribute__((ext_vector_type(2)));
typedef u32   u32x4  __attribute__((ext_vector_type(4)));
typedef __bf16 bf16x8 __attribute__((ext_vector_type(8)));
typedef float f32x4  __attribute__((ext_vector_type(4)));

#define DEV static __device__ __forceinline__

// problem constants
#define BT   64
#define TT   800
#define UU   64
#define HH   512
#define SENT 60
#define NG   2048
#define MOUT 121
#define K1P 576    // X1 = [h1:512][strk:3][w:60][pad:1]
#define K2P 1088   // X2 = [h1:512][h2:512][w:60 @1024][strk:3 @1084][pad:1]
#define KMD 1024   // Xm = [h1:512][h2:512]
#define KSW 512
#define R1W 576    // h1 ring row: [h1:512][w:60][pad:4]

#define NBG 4
#define G1B 16
#define G2B 16
#define MDB 2
#define NBLK (NBG*(G1B+G2B+MDB))   // 136 real blocks
#define NBALL 256                  // + 120 heater blocks

// workspace layout (bytes)
#define OFF_BAR 0
#define OFF_H1  4096
#define OFF_H2  (OFF_H1 + 4*BT*R1W*2)
#define OFF_CM  (OFF_H2 + 4*BT*HH*2)
#define OFF_W1  (OFF_CM + 32768)
#define OFF_W2  (OFF_W1 + NG*K1P*2)
#define OFF_WSW (OFF_W2 + NG*K2P*2)
#define OFF_WMD (OFF_WSW + 32*KSW*2)
#define OFF_B1  (OFF_WMD + 128*KMD*2)
#define OFF_B2  (OFF_B1 + NG*4)
#define OFF_BSW (OFF_B2 + NG*4)
#define OFF_BMD (OFF_BSW + 256)
#define WS_NEED (OFF_BMD + 512)
#define ZERO_BYTES OFF_CM   // counters + done flag + h1/h2 rings

#define DONE_DW 16          // bar dword index of heater done-counter

// output offsets (floats)
#define OW_EOS 0
#define OW_W   (BT*TT)
#define OW_MU1 (OW_W   + BT*TT*20)
#define OW_MU2 (OW_MU1 + BT*TT*20)
#define OW_S1  (OW_MU2 + BT*TT*20)
#define OW_S2  (OW_S1  + BT*TT*20)
#define OW_RHO (OW_S2  + BT*TT*20)

DEV u16 f2bf(float f){
  u32 u = __builtin_bit_cast(u32, f);
  u = (u + 0x7FFFu + ((u >> 16) & 1u)) >> 16;
  return (u16)u;
}
DEV bf16x8 ld8(const u16* p){ return __builtin_bit_cast(bf16x8, *(const u16x8*)p); }
DEV f32x4 mfma16(bf16x8 a, bf16x8 b, f32x4 c){
  return __builtin_amdgcn_mfma_f32_16x16x32_bf16(a, b, c, 0, 0, 0);
}
DEV float sig_(float x){ return 1.f/(1.f + __expf(-x)); }
DEV float tanh_(float x){
  float ax = fabsf(x);
  float e  = __expf(-2.f*ax);
  float t2 = (1.f - e)/(1.f + e);
  return x < 0.f ? -t2 : t2;
}
DEV void pin_agpr(bf16x8& v){
  u32x4 t = __builtin_bit_cast(u32x4, v);
  asm volatile("" : "+a"(t));
  v = __builtin_bit_cast(bf16x8, t);
}

// ---- L3-coherent (device-scope) memory helpers ----
DEV void ld_tile4(const u16* p, u16x8& a0, u16x8& a1, u16x8& a2, u16x8& a3){
  asm volatile(
    "global_load_dwordx4 %0, %4, off sc0 sc1\n\t"
    "global_load_dwordx4 %1, %4, off offset:256 sc0 sc1\n\t"
    "global_load_dwordx4 %2, %4, off offset:512 sc0 sc1\n\t"
    "global_load_dwordx4 %3, %4, off offset:768 sc0 sc1\n\t"
    "s_waitcnt vmcnt(0)"
    : "=&v"(a0), "=&v"(a1), "=&v"(a2), "=&v"(a3)
    : "v"(p) : "memory");
}
DEV void ld_tile8(const u16* p1, const u16* p2,
                  u16x8& a0,u16x8& a1,u16x8& a2,u16x8& a3,
                  u16x8& b0,u16x8& b1,u16x8& b2,u16x8& b3){
  asm volatile(
    "global_load_dwordx4 %0, %8, off sc0 sc1\n\t"
    "global_load_dwordx4 %1, %8, off offset:256 sc0 sc1\n\t"
    "global_load_dwordx4 %2, %8, off offset:512 sc0 sc1\n\t"
    "global_load_dwordx4 %3, %8, off offset:768 sc0 sc1\n\t"
    "global_load_dwordx4 %4, %9, off sc0 sc1\n\t"
    "global_load_dwordx4 %5, %9, off offset:256 sc0 sc1\n\t"
    "global_load_dwordx4 %6, %9, off offset:512 sc0 sc1\n\t"
    "global_load_dwordx4 %7, %9, off offset:768 sc0 sc1\n\t"
    "s_waitcnt vmcnt(0)"
    : "=&v"(a0),"=&v"(a1),"=&v"(a2),"=&v"(a3),
      "=&v"(b0),"=&v"(b1),"=&v"(b2),"=&v"(b3)
    : "v"(p1), "v"(p2) : "memory");
}
// tile8 + one dwordx2 (w-tail) in the same asm so a single vmcnt(0) covers all
DEV void ld_tile8w(const u16* p1, const u16* p2, const u16* p3,
                   u16x8& a0,u16x8& a1,u16x8& a2,u16x8& a3,
                   u16x8& b0,u16x8& b1,u16x8& b2,u16x8& b3, u32x2& w){
  asm volatile(
    "global_load_dwordx4 %0, %9, off sc0 sc1\n\t"
    "global_load_dwordx4 %1, %9, off offset:256 sc0 sc1\n\t"
    "global_load_dwordx4 %2, %9, off offset:512 sc0 sc1\n\t"
    "global_load_dwordx4 %3, %9, off offset:768 sc0 sc1\n\t"
    "global_load_dwordx4 %4, %10, off sc0 sc1\n\t"
    "global_load_dwordx4 %5, %10, off offset:256 sc0 sc1\n\t"
    "global_load_dwordx4 %6, %10, off offset:512 sc0 sc1\n\t"
    "global_load_dwordx4 %7, %10, off offset:768 sc0 sc1\n\t"
    "global_load_dwordx2 %8, %11, off sc0 sc1\n\t"
    "s_waitcnt vmcnt(0)"
    : "=&v"(a0),"=&v"(a1),"=&v"(a2),"=&v"(a3),
      "=&v"(b0),"=&v"(b1),"=&v"(b2),"=&v"(b3),"=&v"(w)
    : "v"(p1), "v"(p2), "v"(p3) : "memory");
}
DEV void st_dword_sc(u32* p, u32 v){
  asm volatile("global_store_dword %0, %1, off sc0 sc1" :: "v"(p), "v"(v) : "memory");
}
DEV void st_dwordx2_sc(u32* p, u32 a, u32 b){
  u32x2 v = {a, b};
  asm volatile("global_store_dwordx2 %0, %1, off sc0 sc1" :: "v"(p), "v"(v) : "memory");
}
DEV void vmwait0(){ asm volatile("s_waitcnt vmcnt(0)" ::: "memory"); }

// counter barrier: per group, one 64B line holding 3 u32 counters at dword
// offsets 0 (role0), 4 (role1), 8 (role2). Producers: one relaxed atomic
// add per step. Consumers: wave0 lanes 0..2 busy-load the line and compare
// all three thresholds with one __all().
DEV void poll_cnts(const u32* cnts, int T0, int T1, int T2){
  if (T0 <= 0 && T1 <= 0 && T2 <= 0) return;
  const int lane = threadIdx.x & 63;
  int thr = (int)0x80000000;   // lanes >=3 always pass
  const u32* p = cnts;
  if (lane == 0)      { thr = T0; p = cnts;     }
  else if (lane == 1) { thr = T1; p = cnts + 4; }
  else if (lane == 2) { thr = T2; p = cnts + 8; }
  for(;;){
    u32 v;
    asm volatile("global_load_dword %0, %1, off sc0 sc1\n\ts_waitcnt vmcnt(0)"
      : "=&v"(v) : "v"(p) : "memory");
    if (__all((int)v >= thr)) return;
  }
}
DEV void arrive(u32* cnt){
  __hip_atomic_fetch_add(cnt, 1u, __ATOMIC_RELAXED, __HIP_MEMORY_SCOPE_AGENT);
}

// ---------------- weight/bias/mask pre-pack ----------
__global__ __launch_bounds__(256) void pack_kernel(
    const float* __restrict__ Wih1, const float* __restrict__ Whh1,
    const float* __restrict__ bih1, const float* __restrict__ bhh1,
    const float* __restrict__ Wih2, const float* __restrict__ Whh2,
    const float* __restrict__ bih2, const float* __restrict__ bhh2,
    const float* __restrict__ Wsw,  const float* __restrict__ bsw,
    const float* __restrict__ Wmdn, const float* __restrict__ bmdn,
    const float* __restrict__ onehots, char* __restrict__ ws)
{
  u16* Wp1  = (u16*)(ws + OFF_W1);
  u16* Wp2  = (u16*)(ws + OFF_W2);
  u16* Wswp = (u16*)(ws + OFF_WSW);
  u16* Wmdp = (u16*)(ws + OFF_WMD);
  float* b1p  = (float*)(ws + OFF_B1);
  float* b2p  = (float*)(ws + OFF_B2);
  float* bswp = (float*)(ws + OFF_BSW);
  float* bmdp = (float*)(ws + OFF_BMD);
  u64* cmask = (u64*)(ws + OFF_CM);

  const int SA = NG*K1P, SB = NG*K2P, SC = 32*KSW, SD = 128*KMD;
  const int SE = NG + NG + 32 + 128, SF = BT*SENT;
  const int total = SA+SB+SC+SD+SE+SF;
  for (int i = blockIdx.x*blockDim.x + threadIdx.x; i < total; i += gridDim.x*blockDim.x){
    if (i < SA){
      const int n = i / K1P, k = i - n*K1P;
      const int r = (n&3)*HH + (n>>2);
      float f;
      if (k < 512)      f = Whh1[r*HH + k];
      else if (k < 515) f = Wih1[r*63 + (k-512)];
      else if (k < 575) f = Wih1[r*63 + 3 + (k-515)];
      else              f = 0.f;
      Wp1[i] = f2bf(f);
    } else if (i < SA+SB){
      const int j = i - SA;
      const int n = j / K2P, k = j - n*K2P;
      const int r = (n&3)*HH + (n>>2);
      float f;
      if (k < 512)       f = Wih2[r*575 + 3 + k];           // h1
      else if (k < 1024) f = Whh2[r*HH + (k-512)];          // h2
      else if (k < 1084) f = Wih2[r*575 + 515 + (k-1024)];  // w
      else if (k < 1087) f = Wih2[r*575 + (k-1084)];        // strk
      else               f = 0.f;
      Wp2[j] = f2bf(f);
    } else if (i < SA+SB+SC){
      const int j = i - SA - SB;
      const int n = j >> 9, k = j & 511;
      Wswp[j] = f2bf(n < 30 ? Wsw[n*KSW + k] : 0.f);
    } else if (i < SA+SB+SC+SD){
      const int j = i - SA - SB - SC;
      const int n = j >> 10, k = j & 1023;
      float f = 0.f;
      if (n < MOUT) f = (k < 512) ? Wmdn[n*1536 + k]
                                  : (Wmdn[n*1536 + 512 + (k-512)] + Wmdn[n*1536 + 1024 + (k-512)]);
      Wmdp[j] = f2bf(f);
    } else if (i < SA+SB+SC+SD+SE){
      int j = i - SA - SB - SC - SD;
      if (j < NG){ const int r=(j&3)*HH+(j>>2); b1p[j] = bih1[r] + bhh1[r]; }
      else if ((j -= NG) < NG){ const int r=(j&3)*HH+(j>>2); b2p[j] = bih2[r] + bhh2[r]; }
      else if ((j -= NG) < 32){ bswp[j] = (j < 30) ? bsw[j] : 0.f; }
      else { j -= 32; bmdp[j] = (j < MOUT) ? bmdn[j] : 0.f; }
    } else {
      const int j = i - SA - SB - SC - SD - SE;
      const int b = j / SENT, c = j - b*SENT;
      const float* oh = onehots + b*UU*SENT + c;
      u64 m = 0;
#pragma unroll 1
      for (int u = 0; u < UU; ++u) if (oh[u*SENT] > 0.5f) m |= (1ull << u);
      cmask[j] = m;
    }
  }
}

// ---------------- LDS layouts ----------------
struct G1S {
  float c[512]; float kk[160];
  u16   X1[16*584];
  union { float gates[4*16*33]; struct { float pp[1024]; float phi[1024]; } a; } u;
  float aa[160], bb[160];
  float smv[1024];
  u64   cm[960];
};
struct G2S {        // role1: no attention scratch
  float c[512];
  u16   X2[16*1096];
  float gates[4*16*33];
};
struct MDS { u16 X[16*1032]; float par[16*68]; };
union alignas(16) BigU { G1S g1; G2S g2; MDS md; };

struct WswF { bf16x8 f[8]; };

// attention for step (tw-1): p = h1 @ Wsw^T from staged X (cols 0..511),
// kappa accumulates in kk, writes bf16 w into the X tile tail at tailoff.
// tw==0 => copy wprev into tail. (role0 only)
DEV void attn_tail(int tw, int bg, u16* X, int xstride, int tailoff,
                   float* pp, float* aa, float* bb, float* kk, float* phi,
                   const float* smv, const u64* cmL, WswF wf,
                   float bswa, float bswb, float bswk,
                   const float* __restrict__ wprev)
{
  const int tid = threadIdx.x;
  if (tw == 0){
    for (int i = tid; i < 16*SENT; i += 256){
      const int b = i / SENT, c = i - b*SENT;
      X[b*xstride + tailoff + c] = f2bf(wprev[(bg*16 + b)*SENT + c]);
    }
    return;
  }
  const int wave = tid >> 6, lane = tid & 63;
  const int quad = lane >> 4, l15 = lane & 15;
  {
    f32x4 acc = {0.f,0.f,0.f,0.f};
    const u16* ap = X + l15*xstride + quad*8 + (wave>>1)*256;
#pragma unroll
    for (int j = 0; j < 8; ++j) acc = mfma16(ld8(ap + j*32), wf.f[j], acc);
    float* dst = pp + (wave>>1)*512;
    const int n = (wave&1)*16 + l15;
#pragma unroll
    for (int r = 0; r < 4; ++r) dst[(quad*4 + r)*32 + n] = acc[r];
  }
  __syncthreads();
  if (tid < 160){
    const int b = tid/10, j = tid - b*10;
    aa[tid] = __expf(pp[b*32 + j]      + pp[512 + b*32 + j]      + bswa);
    bb[tid] = __expf(pp[b*32 + 10 + j] + pp[512 + b*32 + 10 + j] + bswb);
    kk[tid] += __expf(pp[b*32 + 20 + j] + pp[512 + b*32 + 20 + j] + bswk);
  }
  __syncthreads();
  for (int i = tid; i < 1024; i += 256){
    const int b = i >> 6, u = i & 63;
    const float uf = (float)u;
    float acc = 0.f;
#pragma unroll
    for (int j = 0; j < 10; ++j){
      float d = kk[b*10 + j] - uf;
      acc = fmaf(aa[b*10 + j], __expf(-bb[b*10 + j]*d*d), acc);
    }
    phi[i] = acc * smv[i];
  }
  __syncthreads();
  for (int i = tid; i < 16*SENT; i += 256){
    const int b = i / SENT, c = i - b*SENT;
    u64 m = cmL[i];
    float acc = 0.f;
    while (m){ const int u = __builtin_ctzll(m); m &= m - 1; acc += phi[b*64 + u]; }
    X[b*xstride + tailoff + c] = f2bf(acc);
  }
}

// ---------------- main persistent kernel ----------------
__global__ __attribute__((amdgpu_waves_per_eu(1,1))) __launch_bounds__(256)
void rnn_main(
    const float* __restrict__ strks, const float* __restrict__ sm,
    const float* __restrict__ wprev, char* __restrict__ ws,
    float* __restrict__ out)
{
  u32* bar   = (u32*)(ws + OFF_BAR);
  u16* h1pub = (u16*)(ws + OFF_H1);
  u16* h2pub = (u16*)(ws + OFF_H2);
  const u64* cmask = (const u64*)(ws + OFF_CM);
  const u16* Wp1  = (const u16*)(ws + OFF_W1);
  const u16* Wp2  = (const u16*)(ws + OFF_W2);
  const u16* Wswp = (const u16*)(ws + OFF_WSW);
  const u16* Wmdp = (const u16*)(ws + OFF_WMD);
  const float* b1p  = (const float*)(ws + OFF_B1);
  const float* b2p  = (const float*)(ws + OFF_B2);
  const float* bswp = (const float*)(ws + OFF_BSW);
  const float* bmdp = (const float*)(ws + OFF_BMD);

  __shared__ BigU S;

  const int bid = blockIdx.x, tid = threadIdx.x;
  const int wave = tid >> 6, lane = tid & 63;
  const int quad = lane >> 4, l15 = lane & 15;
  const int sb = tid >> 4, sl = tid & 15;

  if (bid < NBG*G1B){
    // ===== role 0: LSTM1 step t; 16 blocks/group, 128 gate cols each =====
    // Runs TT+1 iterations: the t==TT epilogue only computes attention
    // (w[TT-1]) and publishes it, so role1's te+2 poll closes at te=TT-1.
    const int bg = bid >> 4, s = bid & 15;
    u32* cnts = bar + bg*256;
    bf16x8 w1r[36];
    const int n0 = s*128 + wave*32 + l15, n1 = n0 + 16;
#pragma unroll
    for (int kt = 0; kt < 18; ++kt){
      w1r[2*kt]   = ld8(Wp1 + n0*K1P + quad*8 + kt*32);
      w1r[2*kt+1] = ld8(Wp1 + n1*K1P + quad*8 + kt*32);
    }
#pragma unroll
    for (int i = 0; i < 36; ++i) pin_agpr(w1r[i]);
    WswF wf;
    { const int nsw = (wave&1)*16 + l15, k0 = (wave>>1)*8;
#pragma unroll
      for (int j = 0; j < 8; ++j) wf.f[j] = ld8(Wswp + nsw*KSW + quad*8 + (k0+j)*32);
#pragma unroll
      for (int j = 0; j < 8; ++j) pin_agpr(wf.f[j]);
    }
    const float bias0 = b1p[n0], bias1 = b1p[n1];
    float bswa = 0.f, bswb = 0.f, bswk = 0.f;
    if (tid < 160){ const int j = tid % 10; bswa = bswp[j]; bswb = bswp[10+j]; bswk = bswp[20+j]; }
    for (int i = tid; i < 512; i += 256) S.g1.c[i] = 0.f;
    if (tid < 160) S.g1.kk[tid] = 0.f;
    for (int i = tid; i < 1024; i += 256) S.g1.smv[i] = sm[(bg*16 + (i>>6))*UU + (i&63)];
    for (int i = tid; i < 960;  i += 256) S.g1.cm[i]  = cmask[(bg*16 + i/60)*SENT + i%60];
    if (sl == 0) S.g1.X1[sb*584 + 575] = 0;
    __syncthreads();

    for (int t = 0; t <= TT; ++t){
      float sv = (sl < 3 && t < TT) ? strks[((bg*16 + sb)*TT + t)*3 + sl] : 0.f;
      if (wave == 0) poll_cnts(cnts, 16*t, 16*(t-3), 2*(t-3));
      __syncthreads();
      const u16* h1prev = h1pub + ((t+3)&3)*(BT*R1W);
      {
        u16x8 a0,a1,a2,a3;
        ld_tile4(h1prev + (bg*16 + sb)*R1W + sl*8, a0,a1,a2,a3);
        u16x8* xr = (u16x8*)(S.g1.X1 + sb*584);
        xr[sl] = a0; xr[sl+16] = a1; xr[sl+32] = a2; xr[sl+48] = a3;
        if (sl < 3) S.g1.X1[sb*584 + 512 + sl] = f2bf(sv);
      }
      __syncthreads();
      attn_tail(t, bg, S.g1.X1, 584, 515, S.g1.u.a.pp, S.g1.aa, S.g1.bb, S.g1.kk,
                S.g1.u.a.phi, S.g1.smv, S.g1.cm, wf, bswa, bswb, bswk, wprev);
      __syncthreads();
      if (t < TT){
        f32x4 acc0 = {0.f,0.f,0.f,0.f}, acc1 = {0.f,0.f,0.f,0.f};
        const u16* ap = S.g1.X1 + l15*584 + quad*8;
#pragma unroll
        for (int kt = 0; kt < 18; ++kt){
          bf16x8 av = ld8(ap + kt*32);
          acc0 = mfma16(av, w1r[2*kt],   acc0);
          acc1 = mfma16(av, w1r[2*kt+1], acc1);
        }
        {
          const int gpl = l15 & 3, cbase = wave*8 + (l15 >> 2);
#pragma unroll
          for (int r = 0; r < 4; ++r){
            float* gp = S.g1.u.gates + gpl*528 + (quad*4 + r)*33 + cbase;
            gp[0] = acc0[r] + bias0;
            gp[4] = acc1[r] + bias1;
          }
        }
        __syncthreads();
        u16* h1cur = h1pub + (t&3)*(BT*R1W);
        {
          const int row = tid >> 4, cp = tid & 15;
          const float* gb = S.g1.u.gates + row*33 + 2*cp;
          const int ci = row*32 + 2*cp;
          float c0 = sig_(gb[528])*S.g1.c[ci]   + sig_(gb[0])*tanh_(gb[1056]);
          float c1 = sig_(gb[529])*S.g1.c[ci+1] + sig_(gb[1])*tanh_(gb[1057]);
          S.g1.c[ci] = c0; S.g1.c[ci+1] = c1;
          u32 v = (u32)f2bf(sig_(gb[1584])*tanh_(c0)) |
                  ((u32)f2bf(sig_(gb[1585])*tanh_(c1)) << 16);
          st_dword_sc((u32*)(h1cur + (bg*16 + row)*R1W + s*32 + 2*cp), v);
        }
      }
      if (s == 0 && tid < 240){
        // publish w[t-1] (attn tail, still in X1) into ring slot (t-1)&3
        u16* wring = h1pub + ((t+3)&3)*(BT*R1W);
        const int b = tid/15, j = tid - b*15;
        const u16* xw = S.g1.X1 + b*584 + 515 + 4*j;
        u32 v0 = (u32)xw[0] | ((u32)xw[1] << 16);
        u32 v1 = (u32)xw[2] | ((u32)xw[3] << 16);
        st_dwordx2_sc((u32*)(wring + (bg*16 + b)*R1W + 512 + 4*j), v0, v1);
      }
      vmwait0();
      __syncthreads();
      if (tid == 0) arrive(cnts);
    }
  }
  else if (bid < NBG*(G1B+G2B)){
    // ===== role 1: LSTM2 step te; 16 blocks/group, 128 gate cols, NO attn
    const int b2 = bid - NBG*G1B, bg = b2 >> 4, s = b2 & 15;
    u32* cnts = bar + bg*256;
    bf16x8 w2r[68];
    const int n0 = s*128 + wave*32 + l15, n1 = n0 + 16;
#pragma unroll
    for (int kt = 0; kt < 34; ++kt){
      w2r[2*kt]   = ld8(Wp2 + n0*K2P + quad*8 + kt*32);
      w2r[2*kt+1] = ld8(Wp2 + n1*K2P + quad*8 + kt*32);
    }
#pragma unroll
    for (int i = 0; i < 68; ++i) pin_agpr(w2r[i]);
    const float bias0 = b2p[n0], bias1 = b2p[n1];
    for (int i = tid; i < 512; i += 256) S.g2.c[i] = 0.f;
    if (sl == 0) S.g2.X2[sb*1096 + 1087] = 0;
    __syncthreads();

    for (int te = 0; te < TT; ++te){
      float sv = (sl < 3) ? strks[((bg*16 + sb)*TT + te)*3 + sl] : 0.f;
      if (wave == 0) poll_cnts(cnts, 16*(te+2), 16*te, 2*(te-3));
      __syncthreads();
      const u16* h1te = h1pub + (te&3)*(BT*R1W);
      const u16* h2pv = h2pub + ((te+3)&3)*(BT*HH);
      {
        u16x8 a0,a1,a2,a3,b0,b1,b2v,b3; u32x2 wv;
        ld_tile8w(h1te + (bg*16 + sb)*R1W + sl*8,
                  h2pv + (bg*16 + sb)*HH  + sl*8,
                  h1te + (bg*16 + sb)*R1W + 512 + sl*4,
                  a0,a1,a2,a3, b0,b1,b2v,b3, wv);
        u16x8* xr = (u16x8*)(S.g2.X2 + sb*1096);
        xr[sl] = a0; xr[sl+16] = a1; xr[sl+32] = a2; xr[sl+48] = a3;
        xr[64+sl] = b0; xr[64+sl+16] = b1; xr[64+sl+32] = b2v; xr[64+sl+48] = b3;
        if (sl < 15){
          u32* wp = (u32*)(S.g2.X2 + sb*1096 + 1024 + 4*sl);
          wp[0] = wv.x; wp[1] = wv.y;
        }
        if (sl < 3) S.g2.X2[sb*1096 + 1084 + sl] = f2bf(sv);
      }
      __syncthreads();
      f32x4 acc0 = {0.f,0.f,0.f,0.f}, acc1 = {0.f,0.f,0.f,0.f};
      const u16* ap = S.g2.X2 + l15*1096 + quad*8;
#pragma unroll
      for (int kt = 0; kt < 34; ++kt){
        bf16x8 av = ld8(ap + kt*32);
        acc0 = mfma16(av, w2r[2*kt],   acc0);
        acc1 = mfma16(av, w2r[2*kt+1], acc1);
      }
      {
        const int gpl = l15 & 3, cbase = wave*8 + (l15 >> 2);
#pragma unroll
        for (int r = 0; r < 4; ++r){
          float* gp = S.g2.gates + gpl*528 + (quad*4 + r)*33 + cbase;
          gp[0] = acc0[r] + bias0;
          gp[4] = acc1[r] + bias1;
        }
      }
      __syncthreads();
      u16* h2cur = h2pub + (te&3)*(BT*HH);
      {
        const int row = tid >> 4, cp = tid & 15;
        const float* gb = S.g2.gates + row*33 + 2*cp;
        const int ci = row*32 + 2*cp;
        float c0 = sig_(gb[528])*S.g2.c[ci]   + sig_(gb[0])*tanh_(gb[1056]);
        float c1 = sig_(gb[529])*S.g2.c[ci+1] + sig_(gb[1])*tanh_(gb[1057]);
        S.g2.c[ci] = c0; S.g2.c[ci+1] = c1;
        u32 v = (u32)f2bf(sig_(gb[1584])*tanh_(c0)) |
                ((u32)f2bf(sig_(gb[1585])*tanh_(c1)) << 16);
        st_dword_sc((u32*)(h2cur + (bg*16 + row)*HH + s*32 + 2*cp), v);
      }
      vmwait0();
      __syncthreads();
      if (tid == 0) arrive(cnts + 4);
    }
  }
  else if (bid < NBLK){
    // ===== role 2: MDN head, step te (signals after staging) =====
    const int b2 = bid - NBG*(G1B+G2B), bg = b2 >> 1, s = b2 & 1;
    u32* cnts = bar + bg*256;
    bf16x8 wmr[32];
    const int n0 = s*64 + wave*16 + l15;
#pragma unroll
    for (int kt = 0; kt < 32; ++kt) wmr[kt] = ld8(Wmdp + n0*KMD + quad*8 + kt*32);
#pragma unroll
    for (int i = 0; i < 32; ++i) pin_agpr(wmr[i]);
    const float bias0 = bmdp[n0];
    __syncthreads();

    for (int te = 0; te < TT; ++te){
      if (wave == 0) poll_cnts(cnts, 0, 16*(te+1), 0);
      __syncthreads();
      const u16* h1te = h1pub + (te&3)*(BT*R1W);
      const u16* h2te = h2pub + (te&3)*(BT*HH);
      {
        u16x8 a0,a1,a2,a3,b0,b1,b2v,b3;
        ld_tile8(h1te + (bg*16 + sb)*R1W + sl*8, h2te + (bg*16 + sb)*HH + sl*8,
                 a0,a1,a2,a3, b0,b1,b2v,b3);
        u16x8* xr = (u16x8*)(S.md.X + sb*1032);
        xr[sl] = a0; xr[sl+16] = a1; xr[sl+32] = a2; xr[sl+48] = a3;
        xr[64+sl] = b0; xr[64+sl+16] = b1; xr[64+sl+32] = b2v; xr[64+sl+48] = b3;
      }
      __syncthreads();
      if (tid == 0) arrive(cnts + 8);   // ring reads done
      f32x4 acc = {0.f,0.f,0.f,0.f};
      const u16* ap = S.md.X + l15*1032 + quad*8;
#pragma unroll
      for (int kt = 0; kt < 32; ++kt) acc = mfma16(ld8(ap + kt*32), wmr[kt], acc);
#pragma unroll
      for (int r = 0; r < 4; ++r)
        S.md.par[(quad*4 + r)*68 + wave*16 + l15] = acc[r] + bias0;
      __syncthreads();
      for (int i = tid; i < 1024; i += 256){
        const int b = i >> 6, lc = i & 63, gc = s*64 + lc;
        const int bt = (bg*16 + b)*TT + te;
        const float v = S.md.par[b*68 + lc];
        if (gc >= 20 && gc < 40)        out[OW_MU1 + bt*20 + (gc-20)]  = v;
        else if (gc >= 40 && gc < 60)   out[OW_MU2 + bt*20 + (gc-40)]  = v;
        else if (gc >= 60 && gc < 80)   out[OW_S1  + bt*20 + (gc-60)]  = __expf(v);
        else if (gc >= 80 && gc < 100)  out[OW_S2  + bt*20 + (gc-80)]  = __expf(v);
        else if (gc >= 100 && gc < 120) out[OW_RHO + bt*20 + (gc-100)] = tanh_(v);
        else if (gc == 120)             out[OW_EOS + bt]               = sig_(v);
      }
      if (s == 0 && tid < 16){
        const int b = tid;
        const int bt = (bg*16 + b)*TT + te;
        float mx = -1e30f;
        for (int c = 0; c < 20; ++c) mx = fmaxf(mx, S.md.par[b*68 + c]);
        float sum = 0.f;
        for (int c = 0; c < 20; ++c) sum += __expf(S.md.par[b*68 + c] - mx);
        const float inv = 1.f/sum;
        for (int c = 0; c < 20; ++c)
          out[OW_W + bt*20 + c] = __expf(S.md.par[b*68 + c] - mx)*inv;
      }
    }
    // signal heaters: all 8 role2 blocks bump the done counter at exit
    if (tid == 0) arrive(bar + DONE_DW);
  }
  else {
    // ===== heater: pure-VALU spinner to keep DPM clocks up ==============
    // 4 independent FMA chains, ~4k dependent steps (~8us) between polls of
    // the done counter (one coalesced same-address load per wave). Exits
    // when all 8 role2 blocks have arrived. No other memory traffic.
    const u32* dp = bar + DONE_DW;
    float x0 = 1.0f + (float)tid * 1e-6f;
    float x1 = 1.1f, x2 = 1.2f, x3 = 1.3f;
    for(;;){
      u32 v;
      asm volatile("global_load_dword %0, %1, off sc0 sc1\n\ts_waitcnt vmcnt(0)"
        : "=&v"(v) : "v"(dp) : "memory");
      if (v >= (u32)(NBG*MDB)) break;
#pragma unroll 16
      for (int i = 0; i < 4096; ++i){
        x0 = fmaf(x0, 1.0000001f, 1e-9f);
        x1 = fmaf(x1, 1.0000001f, 1e-9f);
        x2 = fmaf(x2, 1.0000001f, 1e-9f);
        x3 = fmaf(x3, 1.0000001f, 1e-9f);
      }
      asm volatile("" : "+v"(x0), "+v"(x1), "+v"(x2), "+v"(x3));
    }
  }
}

extern "C" void kernel_launch(void* const* d_in, const int* in_sizes, int n_in,
                              void* d_out, int out_size, void* d_ws, size_t ws_size,
                              hipStream_t stream)
{
  const float* strks   = (const float*)d_in[0];
  const float* sentsm  = (const float*)d_in[3];
  const float* onehots = (const float*)d_in[4];
  const float* wprev   = (const float*)d_in[5];
  const float* Wih1 = (const float*)d_in[6];
  const float* Whh1 = (const float*)d_in[7];
  const float* bih1 = (const float*)d_in[8];
  const float* bhh1 = (const float*)d_in[9];
  const float* Wih2 = (const float*)d_in[10];
  const float* Whh2 = (const float*)d_in[11];
  const float* bih2 = (const float*)d_in[12];
  const float* bhh2 = (const float*)d_in[13];
  const float* Wsw  = (const float*)d_in[14];
  const float* bsw  = (const float*)d_in[15];
  const float* Wmdn = (const float*)d_in[16];
  const float* bmdn = (const float*)d_in[17];
  (void)in_sizes; (void)n_in; (void)out_size;

  if (ws_size < (size_t)WS_NEED) return;

  hipMemsetAsync(d_ws, 0, ZERO_BYTES, stream);
  pack_kernel<<<2048, 256, 0, stream>>>(Wih1, Whh1, bih1, bhh1, Wih2, Whh2, bih2, bhh2,
                                        Wsw, bsw, Wmdn, bmdn, onehots, (char*)d_ws);
  rnn_main<<<NBALL, 256, 0, stream>>>(strks, sentsm, wprev, (char*)d_ws, (float*)d_out);
}

// Round 9
// 4568.675 us; speedup vs baseline: 1.2622x; 1.2622x over previous
//
#include <hip/hip_runtime.h>

// Handwriting synthesis RNN — persistent fused kernel, R12.
// R12 = R11's XCD-local idea, made safe. R11 died in the container (no
// data); suspects: s_getreg fault, spin-hang, mixed-mode deadlock. R12:
// (1) XCD detection replaced by a HARDWARE COHERENCE PROBE that tests the
//     exact property used: prime probe line in consumer L2 -> block0 writes
//     it sc0-only + wg-scope atomic -> consumer re-reads sc0. Fresh => same
//     L2 (local ok), stale => fallback. All outcomes safe.
// (2) every spin has a bounded fuse: worst case = wrong answer + counters,
//     never a hung container.
// (3) R11 race fixed: role0 also bumps its agent counter each step; role2
//     (remote, reads sc1 dup rings) waits BOTH agent counters >= 16*(te+2).
// (4) per-group verdict published once (VRD), consumed uniformly by all
//     role0/1/2 blocks of the group -> no mixed-mode deadlock.
// Fallback path is semantically identical to R9 (measured 5550us steady).

typedef unsigned short u16;
typedef unsigned int   u32;
typedef unsigned long long u64;
typedef u16   u16x8  __attribute__((ext_vector_type(8)));
typedef u32   u32x2  __attribute__((ext_vector_type(2)));
typedef u32   u32x4  __attribute__((ext_vector_type(4)));
typedef __bf16 bf16x8 __attribute__((ext_vector_type(8)));
typedef float f32x4  __attribute__((ext_vector_type(4)));

#define DEV static __device__ __forceinline__

// problem constants
#define BT   64
#define TT   800
#define UU   64
#define HH   512
#define SENT 60
#define NG   2048
#define MOUT 121
#define K1P 576
#define K2P 1088
#define KMD 1024
#define KSW 512
#define R1W 576    // h1 ring row: [h1:512][w:60][pad:4]

#define NBG 4
#define G1B 16
#define G2B 16
#define MDB 2
#define NACTIVE (NBG*(G1B+G2B+MDB))   // 136
#define NBALL 256

// workspace layout (bytes)
#define OFF_BAR 0
#define OFF_H1  4096
#define OFF_H2  (OFF_H1 + 4*BT*R1W*2)
#define OFF_CM  (OFF_H2 + 4*BT*HH*2)
#define OFF_W1  (OFF_CM + 32768)
#define OFF_W2  (OFF_W1 + NG*K1P*2)
#define OFF_WSW (OFF_W2 + NG*K2P*2)
#define OFF_WMD (OFF_WSW + 32*KSW*2)
#define OFF_B1  (OFF_WMD + 128*KMD*2)
#define OFF_B2  (OFF_B1 + NG*4)
#define OFF_BSW (OFF_B2 + NG*4)
#define OFF_BMD (OFF_BSW + 256)
#define WS_BASE (OFF_BMD + 512)
#define OFF_H1L WS_BASE
#define OFF_H2L (OFF_H1L + 4*BT*R1W*2)
#define WS_FULL (OFF_H2L + 4*BT*HH*2)
#define ZERO_BYTES OFF_CM
#define ZERO_TAIL  (WS_FULL - OFF_H1L)

// bar dword indices (bar = 4096B = 1024 dwords, all zeroed)
#define AGL(g)  ((g)*64)        // agent line: [0]=role0 [1]=role1 [2]=role2
#define LCL(g)  (256 + (g)*64)  // local line: [0]=role0 [1]=role1
#define GINI  516               // +g : probe prime-arrive counter
#define GV    524               // +g : probe verdict-arrive counter
#define FM_   532               // +g : probe fail mask
#define VRD_  540               // +g : published verdict (0=undecided,1=fb,2=local)
#define PRB(g) (576 + (g)*96)   // probe lines: +0,+16,+32,+48 ; P2 at +64
#define FLG(g) (PRB(g) + 80)    // probe flag line

#define THRMIN ((int)0x80000000)
#define FUSE_INIT (1u<<23)
#define FUSE_STDY (1u<<24)

// output offsets (floats)
#define OW_EOS 0
#define OW_W   (BT*TT)
#define OW_MU1 (OW_W   + BT*TT*20)
#define OW_MU2 (OW_MU1 + BT*TT*20)
#define OW_S1  (OW_MU2 + BT*TT*20)
#define OW_S2  (OW_S1  + BT*TT*20)
#define OW_RHO (OW_S2  + BT*TT*20)

DEV u16 f2bf(float f){
  u32 u = __builtin_bit_cast(u32, f);
  u = (u + 0x7FFFu + ((u >> 16) & 1u)) >> 16;
  return (u16)u;
}
DEV bf16x8 ld8(const u16* p){ return __builtin_bit_cast(bf16x8, *(const u16x8*)p); }
DEV f32x4 mfma16(bf16x8 a, bf16x8 b, f32x4 c){
  return __builtin_amdgcn_mfma_f32_16x16x32_bf16(a, b, c, 0, 0, 0);
}
DEV float sig_(float x){ return 1.f/(1.f + __expf(-x)); }
DEV float tanh_(float x){
  float ax = fabsf(x);
  float e  = __expf(-2.f*ax);
  float t2 = (1.f - e)/(1.f + e);
  return x < 0.f ? -t2 : t2;
}
DEV void pin_agpr(bf16x8& v){
  u32x4 t = __builtin_bit_cast(u32x4, v);
  asm volatile("" : "+a"(t));
  v = __builtin_bit_cast(bf16x8, t);
}

// ---- memory helpers: _g = device scope (sc0 sc1), _l = XCD-local (sc0) ----
DEV void ld_tile4_g(const u16* p, u16x8& a0, u16x8& a1, u16x8& a2, u16x8& a3){
  asm volatile(
    "global_load_dwordx4 %0, %4, off sc0 sc1\n\t"
    "global_load_dwordx4 %1, %4, off offset:256 sc0 sc1\n\t"
    "global_load_dwordx4 %2, %4, off offset:512 sc0 sc1\n\t"
    "global_load_dwordx4 %3, %4, off offset:768 sc0 sc1\n\t"
    "s_waitcnt vmcnt(0)"
    : "=&v"(a0), "=&v"(a1), "=&v"(a2), "=&v"(a3)
    : "v"(p) : "memory");
}
DEV void ld_tile4_l(const u16* p, u16x8& a0, u16x8& a1, u16x8& a2, u16x8& a3){
  asm volatile(
    "global_load_dwordx4 %0, %4, off sc0\n\t"
    "global_load_dwordx4 %1, %4, off offset:256 sc0\n\t"
    "global_load_dwordx4 %2, %4, off offset:512 sc0\n\t"
    "global_load_dwordx4 %3, %4, off offset:768 sc0\n\t"
    "s_waitcnt vmcnt(0)"
    : "=&v"(a0), "=&v"(a1), "=&v"(a2), "=&v"(a3)
    : "v"(p) : "memory");
}
DEV void ld_tile8_g(const u16* p1, const u16* p2,
                    u16x8& a0,u16x8& a1,u16x8& a2,u16x8& a3,
                    u16x8& b0,u16x8& b1,u16x8& b2,u16x8& b3){
  asm volatile(
    "global_load_dwordx4 %0, %8, off sc0 sc1\n\t"
    "global_load_dwordx4 %1, %8, off offset:256 sc0 sc1\n\t"
    "global_load_dwordx4 %2, %8, off offset:512 sc0 sc1\n\t"
    "global_load_dwordx4 %3, %8, off offset:768 sc0 sc1\n\t"
    "global_load_dwordx4 %4, %9, off sc0 sc1\n\t"
    "global_load_dwordx4 %5, %9, off offset:256 sc0 sc1\n\t"
    "global_load_dwordx4 %6, %9, off offset:512 sc0 sc1\n\t"
    "global_load_dwordx4 %7, %9, off offset:768 sc0 sc1\n\t"
    "s_waitcnt vmcnt(0)"
    : "=&v"(a0),"=&v"(a1),"=&v"(a2),"=&v"(a3),
      "=&v"(b0),"=&v"(b1),"=&v"(b2),"=&v"(b3)
    : "v"(p1), "v"(p2) : "memory");
}
DEV void ld_tile8w_g(const u16* p1, const u16* p2, const u16* p3,
                     u16x8& a0,u16x8& a1,u16x8& a2,u16x8& a3,
                     u16x8& b0,u16x8& b1,u16x8& b2,u16x8& b3, u32x2& w){
  asm volatile(
    "global_load_dwordx4 %0, %9, off sc0 sc1\n\t"
    "global_load_dwordx4 %1, %9, off offset:256 sc0 sc1\n\t"
    "global_load_dwordx4 %2, %9, off offset:512 sc0 sc1\n\t"
    "global_load_dwordx4 %3, %9, off offset:768 sc0 sc1\n\t"
    "global_load_dwordx4 %4, %10, off sc0 sc1\n\t"
    "global_load_dwordx4 %5, %10, off offset:256 sc0 sc1\n\t"
    "global_load_dwordx4 %6, %10, off offset:512 sc0 sc1\n\t"
    "global_load_dwordx4 %7, %10, off offset:768 sc0 sc1\n\t"
    "global_load_dwordx2 %8, %11, off sc0 sc1\n\t"
    "s_waitcnt vmcnt(0)"
    : "=&v"(a0),"=&v"(a1),"=&v"(a2),"=&v"(a3),
      "=&v"(b0),"=&v"(b1),"=&v"(b2),"=&v"(b3),"=&v"(w)
    : "v"(p1), "v"(p2), "v"(p3) : "memory");
}
DEV void ld_tile8w_l(const u16* p1, const u16* p2, const u16* p3,
                     u16x8& a0,u16x8& a1,u16x8& a2,u16x8& a3,
                     u16x8& b0,u16x8& b1,u16x8& b2,u16x8& b3, u32x2& w){
  asm volatile(
    "global_load_dwordx4 %0, %9, off sc0\n\t"
    "global_load_dwordx4 %1, %9, off offset:256 sc0\n\t"
    "global_load_dwordx4 %2, %9, off offset:512 sc0\n\t"
    "global_load_dwordx4 %3, %9, off offset:768 sc0\n\t"
    "global_load_dwordx4 %4, %10, off sc0\n\t"
    "global_load_dwordx4 %5, %10, off offset:256 sc0\n\t"
    "global_load_dwordx4 %6, %10, off offset:512 sc0\n\t"
    "global_load_dwordx4 %7, %10, off offset:768 sc0\n\t"
    "global_load_dwordx2 %8, %11, off sc0\n\t"
    "s_waitcnt vmcnt(0)"
    : "=&v"(a0),"=&v"(a1),"=&v"(a2),"=&v"(a3),
      "=&v"(b0),"=&v"(b1),"=&v"(b2),"=&v"(b3),"=&v"(w)
    : "v"(p1), "v"(p2), "v"(p3) : "memory");
}
DEV void st_dword_g(u32* p, u32 v){
  asm volatile("global_store_dword %0, %1, off sc0 sc1" :: "v"(p), "v"(v) : "memory");
}
DEV void st_dword_l(u32* p, u32 v){
  asm volatile("global_store_dword %0, %1, off sc0" :: "v"(p), "v"(v) : "memory");
}
DEV void st_dwordx2_g(u32* p, u32 a, u32 b){
  u32x2 v = {a, b};
  asm volatile("global_store_dwordx2 %0, %1, off sc0 sc1" :: "v"(p), "v"(v) : "memory");
}
DEV void st_dwordx2_l(u32* p, u32 a, u32 b){
  u32x2 v = {a, b};
  asm volatile("global_store_dwordx2 %0, %1, off sc0" :: "v"(p), "v"(v) : "memory");
}
DEV void vmwait0(){ asm volatile("s_waitcnt vmcnt(0)" ::: "memory"); }

// ---- spins (all fused: worst case = wrong result, never a hang) ----
DEV bool spinA_f(const u32* p, int thr, u32 fuse){
  if (thr <= 0) return true;
  for (u32 i = 0; i < fuse; ++i){
    u32 v;
    asm volatile("global_load_dword %0, %1, off sc0 sc1\n\ts_waitcnt vmcnt(0)"
      : "=&v"(v) : "v"(p) : "memory");
    if ((int)v >= thr) return true;
  }
  return false;
}
DEV void spinA(const u32* p, int thr){ (void)spinA_f(p, thr, FUSE_STDY); }
// XCD-local two-counter spin (sc0 loads): lane0 base[0]>=t0, lane1 base[1]>=t1
DEV void spinL2(const u32* base, int t0, int t1){
  if (t0 <= 0 && t1 <= 0) return;
  const int lane = threadIdx.x & 63;
  const u32* p = base + (lane == 1 ? 1 : 0);
  int thr = (lane == 0) ? t0 : (lane == 1 ? t1 : THRMIN);
  for (u32 i = 0; i < FUSE_STDY; ++i){
    u32 v;
    asm volatile("global_load_dword %0, %1, off sc0\n\ts_waitcnt vmcnt(0)"
      : "=&v"(v) : "v"(p) : "memory");
    if (__all((int)v >= thr)) return;
  }
}
// agent two-counter spin: lane0 base[0]>=t0, lane1 base[1]>=t1
DEV void spinA2(const u32* base, int t0, int t1){
  if (t0 <= 0 && t1 <= 0) return;
  const int lane = threadIdx.x & 63;
  const u32* p = base + (lane == 1 ? 1 : 0);
  int thr = (lane == 0) ? t0 : (lane == 1 ? t1 : THRMIN);
  for (u32 i = 0; i < FUSE_STDY; ++i){
    u32 v;
    asm volatile("global_load_dword %0, %1, off sc0 sc1\n\ts_waitcnt vmcnt(0)"
      : "=&v"(v) : "v"(p) : "memory");
    if (__all((int)v >= thr)) return;
  }
}
// R9 fallback agent 3-counter spin (lanes 0..2)
DEV void poll_cnts(const u32* cnts, int T0, int T1, int T2){
  if (T0 <= 0 && T1 <= 0 && T2 <= 0) return;
  const int lane = threadIdx.x & 63;
  int thr = THRMIN;
  const u32* p = cnts;
  if (lane == 0)      { thr = T0; p = cnts;     }
  else if (lane == 1) { thr = T1; p = cnts + 1; }
  else if (lane == 2) { thr = T2; p = cnts + 2; }
  for (u32 i = 0; i < FUSE_STDY; ++i){
    u32 v;
    asm volatile("global_load_dword %0, %1, off sc0 sc1\n\ts_waitcnt vmcnt(0)"
      : "=&v"(v) : "v"(p) : "memory");
    if (__all((int)v >= thr)) return;
  }
}
DEV void arriveA(u32* cnt){
  __hip_atomic_fetch_add(cnt, 1u, __ATOMIC_RELAXED, __HIP_MEMORY_SCOPE_AGENT);
}
DEV void arriveL(u32* cnt){
  __hip_atomic_fetch_add(cnt, 1u, __ATOMIC_RELAXED, __HIP_MEMORY_SCOPE_WORKGROUP);
}

// ---------------- weight/bias/mask pre-pack (unchanged) ----------
__global__ __launch_bounds__(256) void pack_kernel(
    const float* __restrict__ Wih1, const float* __restrict__ Whh1,
    const float* __restrict__ bih1, const float* __restrict__ bhh1,
    const float* __restrict__ Wih2, const float* __restrict__ Whh2,
    const float* __restrict__ bih2, const float* __restrict__ bhh2,
    const float* __restrict__ Wsw,  const float* __restrict__ bsw,
    const float* __restrict__ Wmdn, const float* __restrict__ bmdn,
    const float* __restrict__ onehots, char* __restrict__ ws)
{
  u16* Wp1  = (u16*)(ws + OFF_W1);
  u16* Wp2  = (u16*)(ws + OFF_W2);
  u16* Wswp = (u16*)(ws + OFF_WSW);
  u16* Wmdp = (u16*)(ws + OFF_WMD);
  float* b1p  = (float*)(ws + OFF_B1);
  float* b2p  = (float*)(ws + OFF_B2);
  float* bswp = (float*)(ws + OFF_BSW);
  float* bmdp = (float*)(ws + OFF_BMD);
  u64* cmask = (u64*)(ws + OFF_CM);

  const int SA = NG*K1P, SB = NG*K2P, SC = 32*KSW, SD = 128*KMD;
  const int SE = NG + NG + 32 + 128, SF = BT*SENT;
  const int total = SA+SB+SC+SD+SE+SF;
  for (int i = blockIdx.x*blockDim.x + threadIdx.x; i < total; i += gridDim.x*blockDim.x){
    if (i < SA){
      const int n = i / K1P, k = i - n*K1P;
      const int r = (n&3)*HH + (n>>2);
      float f;
      if (k < 512)      f = Whh1[r*HH + k];
      else if (k < 515) f = Wih1[r*63 + (k-512)];
      else if (k < 575) f = Wih1[r*63 + 3 + (k-515)];
      else              f = 0.f;
      Wp1[i] = f2bf(f);
    } else if (i < SA+SB){
      const int j = i - SA;
      const int n = j / K2P, k = j - n*K2P;
      const int r = (n&3)*HH + (n>>2);
      float f;
      if (k < 512)       f = Wih2[r*575 + 3 + k];
      else if (k < 1024) f = Whh2[r*HH + (k-512)];
      else if (k < 1084) f = Wih2[r*575 + 515 + (k-1024)];
      else if (k < 1087) f = Wih2[r*575 + (k-1084)];
      else               f = 0.f;
      Wp2[j] = f2bf(f);
    } else if (i < SA+SB+SC){
      const int j = i - SA - SB;
      const int n = j >> 9, k = j & 511;
      Wswp[j] = f2bf(n < 30 ? Wsw[n*KSW + k] : 0.f);
    } else if (i < SA+SB+SC+SD){
      const int j = i - SA - SB - SC;
      const int n = j >> 10, k = j & 1023;
      float f = 0.f;
      if (n < MOUT) f = (k < 512) ? Wmdn[n*1536 + k]
                                  : (Wmdn[n*1536 + 512 + (k-512)] + Wmdn[n*1536 + 1024 + (k-512)]);
      Wmdp[j] = f2bf(f);
    } else if (i < SA+SB+SC+SD+SE){
      int j = i - SA - SB - SC - SD;
      if (j < NG){ const int r=(j&3)*HH+(j>>2); b1p[j] = bih1[r] + bhh1[r]; }
      else if ((j -= NG) < NG){ const int r=(j&3)*HH+(j>>2); b2p[j] = bih2[r] + bhh2[r]; }
      else if ((j -= NG) < 32){ bswp[j] = (j < 30) ? bsw[j] : 0.f; }
      else { j -= 32; bmdp[j] = (j < MOUT) ? bmdn[j] : 0.f; }
    } else {
      const int j = i - SA - SB - SC - SD - SE;
      const int b = j / SENT, c = j - b*SENT;
      const float* oh = onehots + b*UU*SENT + c;
      u64 m = 0;
#pragma unroll 1
      for (int u = 0; u < UU; ++u) if (oh[u*SENT] > 0.5f) m |= (1ull << u);
      cmask[j] = m;
    }
  }
}

// ---------------- LDS layouts ----------------
struct G1S {
  float c[512]; float kk[160];
  u16   X1[16*584];
  union { float gates[4*16*33]; struct { float pp[1024]; float phi[1024]; } a; } u;
  float aa[160], bb[160];
  float smv[1024];
  u64   cm[960];
};
struct G2S {
  float c[512];
  u16   X2[16*1096];
  float gates[4*16*33];
};
struct MDS { u16 X[16*1032]; float par[16*68]; };
union alignas(16) BigU { G1S g1; G2S g2; MDS md; };

struct WswF { bf16x8 f[8]; };

DEV void attn_tail(int tw, int bg, u16* X, int xstride, int tailoff,
                   float* pp, float* aa, float* bb, float* kk, float* phi,
                   const float* smv, const u64* cmL, WswF wf,
                   float bswa, float bswb, float bswk,
                   const float* __restrict__ wprev)
{
  const int tid = threadIdx.x;
  if (tw == 0){
    for (int i = tid; i < 16*SENT; i += 256){
      const int b = i / SENT, c = i - b*SENT;
      X[b*xstride + tailoff + c] = f2bf(wprev[(bg*16 + b)*SENT + c]);
    }
    return;
  }
  const int wave = tid >> 6, lane = tid & 63;
  const int quad = lane >> 4, l15 = lane & 15;
  {
    f32x4 acc = {0.f,0.f,0.f,0.f};
    const u16* ap = X + l15*xstride + quad*8 + (wave>>1)*256;
#pragma unroll
    for (int j = 0; j < 8; ++j) acc = mfma16(ld8(ap + j*32), wf.f[j], acc);
    float* dst = pp + (wave>>1)*512;
    const int n = (wave&1)*16 + l15;
#pragma unroll
    for (int r = 0; r < 4; ++r) dst[(quad*4 + r)*32 + n] = acc[r];
  }
  __syncthreads();
  if (tid < 160){
    const int b = tid/10, j = tid - b*10;
    aa[tid] = __expf(pp[b*32 + j]      + pp[512 + b*32 + j]      + bswa);
    bb[tid] = __expf(pp[b*32 + 10 + j] + pp[512 + b*32 + 10 + j] + bswb);
    kk[tid] += __expf(pp[b*32 + 20 + j] + pp[512 + b*32 + 20 + j] + bswk);
  }
  __syncthreads();
  for (int i = tid; i < 1024; i += 256){
    const int b = i >> 6, u = i & 63;
    const float uf = (float)u;
    float acc = 0.f;
#pragma unroll
    for (int j = 0; j < 10; ++j){
      float d = kk[b*10 + j] - uf;
      acc = fmaf(aa[b*10 + j], __expf(-bb[b*10 + j]*d*d), acc);
    }
    phi[i] = acc * smv[i];
  }
  __syncthreads();
  for (int i = tid; i < 16*SENT; i += 256){
    const int b = i / SENT, c = i - b*SENT;
    u64 m = cmL[i];
    float acc = 0.f;
    while (m){ const int u = __builtin_ctzll(m); m &= m - 1; acc += phi[b*64 + u]; }
    X[b*xstride + tailoff + c] = f2bf(acc);
  }
}

// ---------------- role bodies (templated on XCD-locality) ----------------
template<bool L>
DEV void role0_body(char* ws, int g, int s, BigU& S,
                    const float* __restrict__ strks, const float* __restrict__ sm,
                    const float* __restrict__ wprev)
{
  u32* bar   = (u32*)(ws + OFF_BAR);
  u32* cntA  = bar + AGL(g);
  u32* cntL  = bar + LCL(g);
  u16* h1sc  = (u16*)(ws + OFF_H1);
  u16* h1l   = (u16*)(ws + OFF_H1L);
  const u64* cmask = (const u64*)(ws + OFF_CM);
  const u16* Wp1  = (const u16*)(ws + OFF_W1);
  const u16* Wswp = (const u16*)(ws + OFF_WSW);
  const float* b1p  = (const float*)(ws + OFF_B1);
  const float* bswp = (const float*)(ws + OFF_BSW);
  u16* ring = L ? h1l : h1sc;

  const int tid = threadIdx.x;
  const int wave = tid >> 6, lane = tid & 63;
  const int quad = lane >> 4, l15 = lane & 15;
  const int sb = tid >> 4, sl = tid & 15;
  const int bg = g;

  bf16x8 w1r[36];
  const int n0 = s*128 + wave*32 + l15, n1 = n0 + 16;
#pragma unroll
  for (int kt = 0; kt < 18; ++kt){
    w1r[2*kt]   = ld8(Wp1 + n0*K1P + quad*8 + kt*32);
    w1r[2*kt+1] = ld8(Wp1 + n1*K1P + quad*8 + kt*32);
  }
#pragma unroll
  for (int i = 0; i < 36; ++i) pin_agpr(w1r[i]);
  WswF wf;
  { const int nsw = (wave&1)*16 + l15, k0 = (wave>>1)*8;
#pragma unroll
    for (int j = 0; j < 8; ++j) wf.f[j] = ld8(Wswp + nsw*KSW + quad*8 + (k0+j)*32);
#pragma unroll
    for (int j = 0; j < 8; ++j) pin_agpr(wf.f[j]);
  }
  const float bias0 = b1p[n0], bias1 = b1p[n1];
  float bswa = 0.f, bswb = 0.f, bswk = 0.f;
  if (tid < 160){ const int j = tid % 10; bswa = bswp[j]; bswb = bswp[10+j]; bswk = bswp[20+j]; }
  for (int i = tid; i < 512; i += 256) S.g1.c[i] = 0.f;
  if (tid < 160) S.g1.kk[tid] = 0.f;
  for (int i = tid; i < 1024; i += 256) S.g1.smv[i] = sm[(bg*16 + (i>>6))*UU + (i&63)];
  for (int i = tid; i < 960;  i += 256) S.g1.cm[i]  = cmask[(bg*16 + i/60)*SENT + i%60];
  if (sl == 0) S.g1.X1[sb*584 + 575] = 0;
  __syncthreads();

  for (int t = 0; t <= TT; ++t){
    float sv = (sl < 3 && t < TT) ? strks[((bg*16 + sb)*TT + t)*3 + sl] : 0.f;
    if (wave == 0){
      if (L){
        spinA(cntA + 2, 2*(t-3));
        spinL2(cntL, 16*t, 16*(t-3));
      } else {
        poll_cnts(cntA, 16*t, 16*(t-3), 2*(t-3));
      }
    }
    __syncthreads();
    const u16* h1prev = ring + ((t+3)&3)*(BT*R1W);
    {
      u16x8 a0,a1,a2,a3;
      if (L) ld_tile4_l(h1prev + (bg*16 + sb)*R1W + sl*8, a0,a1,a2,a3);
      else   ld_tile4_g(h1prev + (bg*16 + sb)*R1W + sl*8, a0,a1,a2,a3);
      u16x8* xr = (u16x8*)(S.g1.X1 + sb*584);
      xr[sl] = a0; xr[sl+16] = a1; xr[sl+32] = a2; xr[sl+48] = a3;
      if (sl < 3) S.g1.X1[sb*584 + 512 + sl] = f2bf(sv);
    }
    __syncthreads();
    if (L){
      // dup h1(t-1) cols [s*32, s*32+32) into the sc1 ring for role2;
      // drains under attn + the end-of-step vmwait.
      const int row = tid >> 4, cp = tid & 15;
      const u16* xp = S.g1.X1 + row*584 + s*32 + 2*cp;
      u32 v = (u32)xp[0] | ((u32)xp[1] << 16);
      st_dword_g((u32*)(h1sc + ((t+3)&3)*(BT*R1W) + (bg*16 + row)*R1W + s*32 + 2*cp), v);
    }
    attn_tail(t, bg, S.g1.X1, 584, 515, S.g1.u.a.pp, S.g1.aa, S.g1.bb, S.g1.kk,
              S.g1.u.a.phi, S.g1.smv, S.g1.cm, wf, bswa, bswb, bswk, wprev);
    __syncthreads();
    if (t < TT){
      f32x4 acc0 = {0.f,0.f,0.f,0.f}, acc1 = {0.f,0.f,0.f,0.f};
      const u16* ap = S.g1.X1 + l15*584 + quad*8;
#pragma unroll
      for (int kt = 0; kt < 18; ++kt){
        bf16x8 av = ld8(ap + kt*32);
        acc0 = mfma16(av, w1r[2*kt],   acc0);
        acc1 = mfma16(av, w1r[2*kt+1], acc1);
      }
      {
        const int gpl = l15 & 3, cbase = wave*8 + (l15 >> 2);
#pragma unroll
        for (int r = 0; r < 4; ++r){
          float* gp = S.g1.u.gates + gpl*528 + (quad*4 + r)*33 + cbase;
          gp[0] = acc0[r] + bias0;
          gp[4] = acc1[r] + bias1;
        }
      }
      __syncthreads();
      u16* h1cur = ring + (t&3)*(BT*R1W);
      {
        const int row = tid >> 4, cp = tid & 15;
        const float* gb = S.g1.u.gates + row*33 + 2*cp;
        const int ci = row*32 + 2*cp;
        float c0 = sig_(gb[528])*S.g1.c[ci]   + sig_(gb[0])*tanh_(gb[1056]);
        float c1 = sig_(gb[529])*S.g1.c[ci+1] + sig_(gb[1])*tanh_(gb[1057]);
        S.g1.c[ci] = c0; S.g1.c[ci+1] = c1;
        u32 v = (u32)f2bf(sig_(gb[1584])*tanh_(c0)) |
                ((u32)f2bf(sig_(gb[1585])*tanh_(c1)) << 16);
        u32* dst = (u32*)(h1cur + (bg*16 + row)*R1W + s*32 + 2*cp);
        if (L) st_dword_l(dst, v); else st_dword_g(dst, v);
      }
    }
    if (s == 0 && tid < 240){
      u16* wring = ring + ((t+3)&3)*(BT*R1W);
      const int b = tid/15, j = tid - b*15;
      const u16* xw = S.g1.X1 + b*584 + 515 + 4*j;
      u32 v0 = (u32)xw[0] | ((u32)xw[1] << 16);
      u32 v1 = (u32)xw[2] | ((u32)xw[3] << 16);
      u32* dst = (u32*)(wring + (bg*16 + b)*R1W + 512 + 4*j);
      if (L) st_dwordx2_l(dst, v0, v1); else st_dwordx2_g(dst, v0, v1);
    }
    vmwait0();
    __syncthreads();
    if (tid == 0){
      if (L){ arriveL(cntL); arriveA(cntA); }
      else  { arriveA(cntA); }
    }
  }
}

template<bool L>
DEV void role1_body(char* ws, int g, int s, BigU& S,
                    const float* __restrict__ strks)
{
  u32* bar   = (u32*)(ws + OFF_BAR);
  u32* cntA  = bar + AGL(g);
  u32* cntL  = bar + LCL(g);
  u16* h1sc  = (u16*)(ws + OFF_H1);
  u16* h2sc  = (u16*)(ws + OFF_H2);
  u16* h1l   = (u16*)(ws + OFF_H1L);
  u16* h2l   = (u16*)(ws + OFF_H2L);
  const u16* Wp2  = (const u16*)(ws + OFF_W2);
  const float* b2p = (const float*)(ws + OFF_B2);
  const u16* h1ring = L ? h1l : h1sc;
  u16* h2ring = L ? h2l : h2sc;

  const int tid = threadIdx.x;
  const int wave = tid >> 6, lane = tid & 63;
  const int quad = lane >> 4, l15 = lane & 15;
  const int sb = tid >> 4, sl = tid & 15;
  const int bg = g;

  bf16x8 w2r[68];
  const int n0 = s*128 + wave*32 + l15, n1 = n0 + 16;
#pragma unroll
  for (int kt = 0; kt < 34; ++kt){
    w2r[2*kt]   = ld8(Wp2 + n0*K2P + quad*8 + kt*32);
    w2r[2*kt+1] = ld8(Wp2 + n1*K2P + quad*8 + kt*32);
  }
#pragma unroll
  for (int i = 0; i < 68; ++i) pin_agpr(w2r[i]);
  const float bias0 = b2p[n0], bias1 = b2p[n1];
  for (int i = tid; i < 512; i += 256) S.g2.c[i] = 0.f;
  if (sl == 0) S.g2.X2[sb*1096 + 1087] = 0;
  __syncthreads();

  for (int te = 0; te <= TT; ++te){   // te==TT: dup-only epilogue (local mode)
    float sv = (sl < 3 && te < TT) ? strks[((bg*16 + sb)*TT + te)*3 + sl] : 0.f;
    if (wave == 0){
      if (L){
        spinA(cntA + 2, 2*(te-3));
        spinL2(cntL, (te < TT) ? 16*(te+2) : 0, 16*te);
      } else {
        poll_cnts(cntA, (te < TT) ? 16*(te+2) : 0, 16*te, 2*(te-3));
      }
    }
    __syncthreads();
    const u16* h1te = h1ring + (te&3)*(BT*R1W);
    const u16* h2pv = h2ring + ((te+3)&3)*(BT*HH);
    {
      u16x8 a0,a1,a2,a3,b0,b1,b2v,b3; u32x2 wv;
      if (L) ld_tile8w_l(h1te + (bg*16 + sb)*R1W + sl*8,
                         h2pv + (bg*16 + sb)*HH  + sl*8,
                         h1te + (bg*16 + sb)*R1W + 512 + sl*4,
                         a0,a1,a2,a3, b0,b1,b2v,b3, wv);
      else   ld_tile8w_g(h1te + (bg*16 + sb)*R1W + sl*8,
                         h2pv + (bg*16 + sb)*HH  + sl*8,
                         h1te + (bg*16 + sb)*R1W + 512 + sl*4,
                         a0,a1,a2,a3, b0,b1,b2v,b3, wv);
      u16x8* xr = (u16x8*)(S.g2.X2 + sb*1096);
      xr[sl] = a0; xr[sl+16] = a1; xr[sl+32] = a2; xr[sl+48] = a3;
      xr[64+sl] = b0; xr[64+sl+16] = b1; xr[64+sl+32] = b2v; xr[64+sl+48] = b3;
      if (sl < 15){
        u32* wp = (u32*)(S.g2.X2 + sb*1096 + 1024 + 4*sl);
        wp[0] = wv.x; wp[1] = wv.y;
      }
      if (sl < 3) S.g2.X2[sb*1096 + 1084 + sl] = f2bf(sv);
    }
    __syncthreads();
    if (L){
      // dup h2(te-1) cols [s*32, s*32+32) into the sc1 ring for role2
      const int row = tid >> 4, cp = tid & 15;
      const u16* xp = S.g2.X2 + row*1096 + 512 + s*32 + 2*cp;
      u32 v = (u32)xp[0] | ((u32)xp[1] << 16);
      st_dword_g((u32*)(h2sc + ((te+3)&3)*(BT*HH) + (bg*16 + row)*HH + s*32 + 2*cp), v);
    }
    if (te < TT){
      f32x4 acc0 = {0.f,0.f,0.f,0.f}, acc1 = {0.f,0.f,0.f,0.f};
      const u16* ap = S.g2.X2 + l15*1096 + quad*8;
#pragma unroll
      for (int kt = 0; kt < 34; ++kt){
        bf16x8 av = ld8(ap + kt*32);
        acc0 = mfma16(av, w2r[2*kt],   acc0);
        acc1 = mfma16(av, w2r[2*kt+1], acc1);
      }
      {
        const int gpl = l15 & 3, cbase = wave*8 + (l15 >> 2);
#pragma unroll
        for (int r = 0; r < 4; ++r){
          float* gp = S.g2.gates + gpl*528 + (quad*4 + r)*33 + cbase;
          gp[0] = acc0[r] + bias0;
          gp[4] = acc1[r] + bias1;
        }
      }
      __syncthreads();
      u16* h2cur = h2ring + (te&3)*(BT*HH);
      {
        const int row = tid >> 4, cp = tid & 15;
        const float* gb = S.g2.gates + row*33 + 2*cp;
        const int ci = row*32 + 2*cp;
        float c0 = sig_(gb[528])*S.g2.c[ci]   + sig_(gb[0])*tanh_(gb[1056]);
        float c1 = sig_(gb[529])*S.g2.c[ci+1] + sig_(gb[1])*tanh_(gb[1057]);
        S.g2.c[ci] = c0; S.g2.c[ci+1] = c1;
        u32 v = (u32)f2bf(sig_(gb[1584])*tanh_(c0)) |
                ((u32)f2bf(sig_(gb[1585])*tanh_(c1)) << 16);
        u32* dst = (u32*)(h2cur + (bg*16 + row)*HH + s*32 + 2*cp);
        if (L) st_dword_l(dst, v); else st_dword_g(dst, v);
      }
    }
    vmwait0();
    __syncthreads();
    if (tid == 0){
      if (L){ arriveL(cntL + 1); arriveA(cntA + 1); }
      else  { arriveA(cntA + 1); }
    }
  }
}

DEV void role2_body(char* ws, int g, int s, BigU& S, float* __restrict__ out, bool local)
{
  u32* bar   = (u32*)(ws + OFF_BAR);
  u32* cntA  = bar + AGL(g);
  u16* h1sc  = (u16*)(ws + OFF_H1);
  u16* h2sc  = (u16*)(ws + OFF_H2);
  const u16* Wmdp = (const u16*)(ws + OFF_WMD);
  const float* bmdp = (const float*)(ws + OFF_BMD);

  const int tid = threadIdx.x;
  const int wave = tid >> 6, lane = tid & 63;
  const int quad = lane >> 4, l15 = lane & 15;
  const int sb = tid >> 4, sl = tid & 15;
  const int bg = g;

  bf16x8 wmr[32];
  const int n0 = s*64 + wave*16 + l15;
#pragma unroll
  for (int kt = 0; kt < 32; ++kt) wmr[kt] = ld8(Wmdp + n0*KMD + quad*8 + kt*32);
#pragma unroll
  for (int i = 0; i < 32; ++i) pin_agpr(wmr[i]);
  const float bias0 = bmdp[n0];
  __syncthreads();

  for (int te = 0; te < TT; ++te){
    // local: dup rings for step te are written during producer step te+1
    if (wave == 0){
      if (local) spinA2(cntA, 16*(te+2), 16*(te+2));
      else       spinA (cntA + 1, 16*(te+1));
    }
    __syncthreads();
    const u16* h1te = h1sc + (te&3)*(BT*R1W);
    const u16* h2te = h2sc + (te&3)*(BT*HH);
    {
      u16x8 a0,a1,a2,a3,b0,b1,b2v,b3;
      ld_tile8_g(h1te + (bg*16 + sb)*R1W + sl*8, h2te + (bg*16 + sb)*HH + sl*8,
                 a0,a1,a2,a3, b0,b1,b2v,b3);
      u16x8* xr = (u16x8*)(S.md.X + sb*1032);
      xr[sl] = a0; xr[sl+16] = a1; xr[sl+32] = a2; xr[sl+48] = a3;
      xr[64+sl] = b0; xr[64+sl+16] = b1; xr[64+sl+32] = b2v; xr[64+sl+48] = b3;
    }
    __syncthreads();
    if (tid == 0) arriveA(cntA + 2);   // ring reads done
    f32x4 acc = {0.f,0.f,0.f,0.f};
    const u16* ap = S.md.X + l15*1032 + quad*8;
#pragma unroll
    for (int kt = 0; kt < 32; ++kt) acc = mfma16(ld8(ap + kt*32), wmr[kt], acc);
#pragma unroll
    for (int r = 0; r < 4; ++r)
      S.md.par[(quad*4 + r)*68 + wave*16 + l15] = acc[r] + bias0;
    __syncthreads();
    for (int i = tid; i < 1024; i += 256){
      const int b = i >> 6, lc = i & 63, gc = s*64 + lc;
      const int bt = (bg*16 + b)*TT + te;
      const float v = S.md.par[b*68 + lc];
      if (gc >= 20 && gc < 40)        out[OW_MU1 + bt*20 + (gc-20)]  = v;
      else if (gc >= 40 && gc < 60)   out[OW_MU2 + bt*20 + (gc-40)]  = v;
      else if (gc >= 60 && gc < 80)   out[OW_S1  + bt*20 + (gc-60)]  = __expf(v);
      else if (gc >= 80 && gc < 100)  out[OW_S2  + bt*20 + (gc-80)]  = __expf(v);
      else if (gc >= 100 && gc < 120) out[OW_RHO + bt*20 + (gc-100)] = tanh_(v);
      else if (gc == 120)             out[OW_EOS + bt]               = sig_(v);
    }
    if (s == 0 && tid < 16){
      const int b = tid;
      const int bt = (bg*16 + b)*TT + te;
      float mx = -1e30f;
      for (int c = 0; c < 20; ++c) mx = fmaxf(mx, S.md.par[b*68 + c]);
      float sum = 0.f;
      for (int c = 0; c < 20; ++c) sum += __expf(S.md.par[b*68 + c] - mx);
      const float inv = 1.f/sum;
      for (int c = 0; c < 20; ++c)
        out[OW_W + bt*20 + c] = __expf(S.md.par[b*68 + c] - mx)*inv;
    }
  }
}

// ---------------- main persistent kernel ----------------
__global__ __attribute__((amdgpu_waves_per_eu(1,1))) __launch_bounds__(256)
void rnn_main(
    const float* __restrict__ strks, const float* __restrict__ sm,
    const float* __restrict__ wprev, char* __restrict__ ws,
    float* __restrict__ out, int allow_local)
{
  const int bid = blockIdx.x, tid = threadIdx.x;
  const int res = bid & 7, k = bid >> 3;
  int role, g, s;
  if (res < 4){
    g = res;
    if (k < 16){ role = 0; s = k; } else { role = 1; s = k - 16; }
  } else {
    g = res - 4;
    if (k < 2){ role = 2; s = k; } else return;     // inactive filler
  }

  __shared__ BigU S;
  __shared__ int Sdec;

  u32* bar = (u32*)(ws + OFF_BAR);
  u32* vrd = bar + VRD_ + g;

  // ---- coherence-probe init: decide local(2) vs fallback(1) per group ----
  if (allow_local){
    if (role <= 1){
      if (tid == 0){
        u32* gi  = bar + GINI + g;
        u32* gv  = bar + GV   + g;
        u32* fm  = bar + FM_  + g;
        u32* pl  = bar + PRB(g);
        u32* flg = bar + FLG(g);
        // 1. prime the probe lines into THIS block's L2 (sc0 reads)
        {
          u32 d0,d1,d2,d3,d4;
          asm volatile(
            "global_load_dword %0, %5, off sc0\n\t"
            "global_load_dword %1, %6, off sc0\n\t"
            "global_load_dword %2, %7, off sc0\n\t"
            "global_load_dword %3, %8, off sc0\n\t"
            "global_load_dword %4, %9, off sc0\n\t"
            "s_waitcnt vmcnt(0)"
            : "=&v"(d0),"=&v"(d1),"=&v"(d2),"=&v"(d3),"=&v"(d4)
            : "v"(pl),"v"(pl+16),"v"(pl+32),"v"(pl+48),"v"(pl+64) : "memory");
          asm volatile("" :: "v"(d0),"v"(d1),"v"(d2),"v"(d3),"v"(d4));
        }
        __hip_atomic_fetch_add(gi, 1u, __ATOMIC_RELEASE, __HIP_MEMORY_SCOPE_AGENT);
        // 2. group writer = role0 s==0: rewrite probes with XCD-local ops
        if (role == 0 && s == 0){
          (void)spinA_f(gi, 32, FUSE_INIT);
          st_dword_l(pl,      0x5AFE0001u);
          st_dword_l(pl + 16, 0x5AFE0002u);
          st_dword_l(pl + 32, 0x5AFE0003u);
          st_dword_l(pl + 48, 0x5AFE0004u);
          __hip_atomic_fetch_add(pl + 64, 7u, __ATOMIC_RELAXED,
                                 __HIP_MEMORY_SCOPE_WORKGROUP);
          vmwait0();
          st_dword_g(flg, 1u);
        }
        // 3. everyone re-reads after the flag: fresh <=> shared L2
        bool ok = spinA_f(flg, 1, FUSE_INIT);
        if (ok){
          u32 e0,e1,e2,e3,e4;
          asm volatile(
            "global_load_dword %0, %5, off sc0\n\t"
            "global_load_dword %1, %6, off sc0\n\t"
            "global_load_dword %2, %7, off sc0\n\t"
            "global_load_dword %3, %8, off sc0\n\t"
            "global_load_dword %4, %9, off sc0\n\t"
            "s_waitcnt vmcnt(0)"
            : "=&v"(e0),"=&v"(e1),"=&v"(e2),"=&v"(e3),"=&v"(e4)
            : "v"(pl),"v"(pl+16),"v"(pl+32),"v"(pl+48),"v"(pl+64) : "memory");
          ok = (e0 == 0x5AFE0001u) && (e1 == 0x5AFE0002u) &&
               (e2 == 0x5AFE0003u) && (e3 == 0x5AFE0004u) && (e4 == 7u);
        }
        if (!ok)
          __hip_atomic_fetch_or(fm, 1u, __ATOMIC_RELAXED, __HIP_MEMORY_SCOPE_AGENT);
        __hip_atomic_fetch_add(gv, 1u, __ATOMIC_RELEASE, __HIP_MEMORY_SCOPE_AGENT);
        // 4. writer publishes the uniform verdict
        if (role == 0 && s == 0){
          (void)spinA_f(gv, 32, FUSE_INIT);
          u32 f;
          asm volatile("global_load_dword %0, %1, off sc0 sc1\n\ts_waitcnt vmcnt(0)"
            : "=&v"(f) : "v"(fm) : "memory");
          st_dword_g(vrd, (f == 0u) ? 2u : 1u);
        }
        // 5. consume verdict (fused; default fallback)
        u32 dec = 1;
        for (u32 i = 0; i < FUSE_STDY; ++i){
          u32 v;
          asm volatile("global_load_dword %0, %1, off sc0 sc1\n\ts_waitcnt vmcnt(0)"
            : "=&v"(v) : "v"(vrd) : "memory");
          if (v != 0){ dec = v; break; }
        }
        Sdec = (int)dec;
      }
    } else {
      if (tid == 0){
        u32 dec = 1;
        for (u32 i = 0; i < FUSE_STDY; ++i){
          u32 v;
          asm volatile("global_load_dword %0, %1, off sc0 sc1\n\ts_waitcnt vmcnt(0)"
            : "=&v"(v) : "v"(vrd) : "memory");
          if (v != 0){ dec = v; break; }
        }
        Sdec = (int)dec;
      }
    }
  } else {
    if (tid == 0) Sdec = 1;
  }
  __syncthreads();
  const bool local = (Sdec == 2);

  if (role == 0){
    if (local) role0_body<true >(ws, g, s, S, strks, sm, wprev);
    else       role0_body<false>(ws, g, s, S, strks, sm, wprev);
  } else if (role == 1){
    if (local) role1_body<true >(ws, g, s, S, strks);
    else       role1_body<false>(ws, g, s, S, strks);
  } else {
    role2_body(ws, g, s, S, out, local);
  }
}

extern "C" void kernel_launch(void* const* d_in, const int* in_sizes, int n_in,
                              void* d_out, int out_size, void* d_ws, size_t ws_size,
                              hipStream_t stream)
{
  const float* strks   = (const float*)d_in[0];
  const float* sentsm  = (const float*)d_in[3];
  const float* onehots = (const float*)d_in[4];
  const float* wprev   = (const float*)d_in[5];
  const float* Wih1 = (const float*)d_in[6];
  const float* Whh1 = (const float*)d_in[7];
  const float* bih1 = (const float*)d_in[8];
  const float* bhh1 = (const float*)d_in[9];
  const float* Wih2 = (const float*)d_in[10];
  const float* Whh2 = (const float*)d_in[11];
  const float* bih2 = (const float*)d_in[12];
  const float* bhh2 = (const float*)d_in[13];
  const float* Wsw  = (const float*)d_in[14];
  const float* bsw  = (const float*)d_in[15];
  const float* Wmdn = (const float*)d_in[16];
  const float* bmdn = (const float*)d_in[17];
  (void)in_sizes; (void)n_in; (void)out_size;

  if (ws_size < (size_t)WS_BASE) return;
  const int allow_local = (ws_size >= (size_t)WS_FULL) ? 1 : 0;

  hipMemsetAsync(d_ws, 0, ZERO_BYTES, stream);
  if (allow_local)
    hipMemsetAsync((char*)d_ws + OFF_H1L, 0, ZERO_TAIL, stream);
  pack_kernel<<<2048, 256, 0, stream>>>(Wih1, Whh1, bih1, bhh1, Wih2, Whh2, bih2, bhh2,
                                        Wsw, bsw, Wmdn, bmdn, onehots, (char*)d_ws);
  rnn_main<<<NBALL, 256, 0, stream>>>(strks, sentsm, wprev, (char*)d_ws,
                                      (float*)d_out, allow_local);
}